// Round 18
// baseline (82.339 us; speedup 1.0000x reference)
//
#include <hip/hip_runtime.h>

// images=8, patches=3600(=60*60), hor_f=64, ver_f=25(=5*5), 64x64 px, k=5
// FUSED single kernel: fold+unfold per strip, LDS img-ring, NT out stores.
#define OH     60
#define NIMG   8
#define HF     64
#define VF     25
#define NPATCH 3600
#define CDIM   1600                  // HF*VF

typedef float floatx4 __attribute__((ext_vector_type(4)));

#define FH    8                      // h channels per block
#define FC    200                    // FH*VF
#define PJS   64                     // staged-row pj stride (XOR-swizzled)
#define SPP   15                     // patches emitted per strip
#define NACC  19                     // img rows kept per block (SPP+4)
#define JP2   65                     // li2 col stride (odd -> bank spread)
#define ROWSZ (8 * JP2)              // ring slot: 8 h x 65

// grid 256 = 4 strips x 8 hg x 8 im (1 block/CU, im = b&7 XCD-pinned)
__global__ __launch_bounds__(512) void fused_kernel(const float* __restrict__ x,
                                                    float* __restrict__ out) {
    __shared__ float lb[FC * PJS];   // 51.2 KB x staging
    __shared__ float li2[6 * ROWSZ]; // 12.48 KB img ring (6 rows x 8h x 65)
    const int b = blockIdx.x;
    const int im = b & 7;
    const int rem = b >> 3;          // 0..31
    const int hg = rem & 7, strip = rem >> 3;
    const int t = threadIdx.x;
    const int h0 = hg * FH;
    const int pi0 = strip * SPP;
    const int j = t & 63, g = t >> 6;          // g = local h (0..7)

    const float rcj = 1.0f / (float)min(min(j + 1, 64 - j), 5);

    float acc[NACC];
#pragma unroll
    for (int k = 0; k < NACC; ++k) acc[k] = 0.f;

    const float* xb = x + (size_t)im * NPATCH * CDIM + h0 * VF;

    // staging offsets (u = t + 512k < 3000): 60 pj x 50 f4 per patch row
    int off_g[6], off_l[6];
#pragma unroll
    for (int k = 0; k < 6; ++k) {
        int u = t + 512 * k;
        if (u < 3000) {
            int pj = u / 50, c4 = u - 50 * pj;
            off_g[k] = pj * CDIM + (c4 << 2);
            off_l[k] = (c4 << 8) + (pj ^ (c4 & 31));
        }
    }

    // emit decode (round-invariant): u -> (pj, s); fl=4s+c -> ho,di,dj
    int outoff[6], colb[6][4], dic[6][4];
#pragma unroll
    for (int k = 0; k < 6; ++k) {
        int u = t + 512 * k;
        if (u < 3000) {
            int pj = u / 50, s = u - 50 * pj;
            outoff[k] = pj * CDIM + (s << 2);
#pragma unroll
            for (int c = 0; c < 4; ++c) {
                int fl = (s << 2) + c;         // = ho*25 + v, < 200
                int ho = fl / 25, v = fl - 25 * ho;
                int di = v / 5, dj = v - 5 * di;
                colb[k][c] = ho * JP2 + pj + dj;
                dic[k][c] = di;
            }
        }
    }

    float4 stg[6];
    {   // prologue: prefetch first staged row (rho = pi0-4)
        int rho = pi0 - 4;
        if (rho >= 0) {
#pragma unroll
            for (int k = 0; k < 6; ++k)
                if (t + 512 * k < 3000)
                    stg[k] = *reinterpret_cast<const float4*>(
                        xb + (size_t)rho * OH * CDIM + off_g[k]);
        }
    }

#pragma unroll
    for (int r = 0; r < 24; ++r) {
        const int rho = pi0 - 4 + r;           // patch row staged this round
        const bool sv = (r <= 22) && (rho >= 0) && (rho <= 59);

        // ---------- phase 1: stage-write lb  ||  emit patch (pi0 + r - 9) ----------
        if (sv) {
#pragma unroll
            for (int k = 0; k < 6; ++k)
                if (t + 512 * k < 3000) {
                    float4 v = stg[k];
                    int a = off_l[k];
                    lb[a]           = v.x;
                    lb[a + PJS]     = v.y;
                    lb[a + 2 * PJS] = v.z;
                    lb[a + 3 * PJS] = v.w;
                }
        }
        if (r >= 9) {                          // emit reads ring rows r-9..r-5 (all dumped)
            float* op = out + ((size_t)im * NPATCH + (size_t)(pi0 + r - 9) * OH) * CDIM
                            + h0 * VF;
            const int base = (r - 9) % 6;      // compile-time
#pragma unroll
            for (int k = 0; k < 6; ++k)
                if (t + 512 * k < 3000) {
                    floatx4 o;
                    { int sl = base + dic[k][0]; sl -= (sl >= 6) ? 6 : 0;
                      o.x = li2[sl * ROWSZ + colb[k][0]]; }
                    { int sl = base + dic[k][1]; sl -= (sl >= 6) ? 6 : 0;
                      o.y = li2[sl * ROWSZ + colb[k][1]]; }
                    { int sl = base + dic[k][2]; sl -= (sl >= 6) ? 6 : 0;
                      o.z = li2[sl * ROWSZ + colb[k][2]]; }
                    { int sl = base + dic[k][3]; sl -= (sl >= 6) ? 6 : 0;
                      o.w = li2[sl * ROWSZ + colb[k][3]]; }
                    __builtin_nontemporal_store(o,
                        reinterpret_cast<floatx4*>(op + outoff[k]));
                }
        }
        __syncthreads();

        // ---------- phase 2: compute taps || prefetch next row || dump img row ----------
        if (sv) {
#pragma unroll
            for (int di = 0; di < 5; ++di) {
                const int il = r - 4 + di;     // img row index - pi0 (compile-time)
                if (il >= 0 && il < NACC) {
#pragma unroll
                    for (int dj = 0; dj < 5; ++dj) {
                        int c = g * VF + di * 5 + dj;
                        int pjr = j - dj;
                        if ((unsigned)pjr < 60u)
                            acc[il] += lb[c * PJS + (pjr ^ ((c >> 2) & 31))];
                    }
                }
            }
        }
        if (r < 23) {                          // prefetch row rho+1 during compute
            int rho2 = rho + 1;
            if (r + 1 <= 22 && rho2 >= 0 && rho2 <= 59) {
#pragma unroll
                for (int k = 0; k < 6; ++k)
                    if (t + 512 * k < 3000)
                        stg[k] = *reinterpret_cast<const float4*>(
                            xb + (size_t)rho2 * OH * CDIM + off_g[k]);
            }
        }
        if (r >= 4 && r <= 22) {               // img row pi0+r-4 complete -> ring
            const int il = r - 4;              // compile-time
            const int i = pi0 + il;
            float ri = 0.2f;
            if (i < 4) ri = 1.0f / (float)(i + 1);
            else if (i > 59) ri = 1.0f / (float)(64 - i);
            li2[(il % 6) * ROWSZ + g * JP2 + j] = acc[il] * ri * rcj;
        }
        __syncthreads();
    }
}

extern "C" void kernel_launch(void* const* d_in, const int* in_sizes, int n_in,
                              void* d_out, int out_size, void* d_ws, size_t ws_size,
                              hipStream_t stream) {
    const float* x = (const float*)d_in[0];
    float* out = (float*)d_out;

    fused_kernel<<<256, 512, 0, stream>>>(x, out);   // 4 strips x 8 hg x 8 im

    (void)out_size; (void)ws_size; (void)d_ws; (void)in_sizes; (void)n_in;
}